// Round 3
// baseline (3989.435 us; speedup 1.0000x reference)
//
#include <hip/hip_runtime.h>

#define BB 32
#define DD 256
#define TT 1024
#define KK 8192

// ws layout:
//   byte 0     : double loss_acc
//   byte 64    : float  Bf[K]          (32768 B)  -- np-pairwise fp32 ||e_k||^2
//   byte 32832 : int    idx_i[B*T]     (131072 B)

// Bit-exact emulation of numpy pairwise_sum of x[i]^2, n=256:
// n=256 -> two blocks of 128; each block: 8 accumulators stride 8, combined
// ((r0+r1)+(r2+r3))+((r4+r5)+(r6+r7)); halves added. All ops fp32, products
// rounded separately (no contraction): __fmul_rn/__fadd_rn.
__device__ __forceinline__ float np_sq_sum256(const float* __restrict__ base, int stride) {
    float res[2];
    #pragma unroll
    for (int blk = 0; blk < 2; ++blk) {
        const int o = blk * 128;
        float r[8];
        #pragma unroll
        for (int j = 0; j < 8; ++j) {
            const float x = base[(o + j) * stride];
            r[j] = __fmul_rn(x, x);
        }
        for (int i = 8; i < 128; i += 8) {
            #pragma unroll
            for (int j = 0; j < 8; ++j) {
                const float x = base[(o + i + j) * stride];
                r[j] = __fadd_rn(r[j], __fmul_rn(x, x));
            }
        }
        res[blk] = __fadd_rn(__fadd_rn(__fadd_rn(r[0], r[1]), __fadd_rn(r[2], r[3])),
                             __fadd_rn(__fadd_rn(r[4], r[5]), __fadd_rn(r[6], r[7])));
    }
    return __fadd_rn(res[0], res[1]);
}

__global__ __launch_bounds__(256) void bsum_kernel(const float* __restrict__ emb,
                                                   float* __restrict__ Bf) {
    const int k = blockIdx.x * 256 + threadIdx.x;
    Bf[k] = np_sq_sum256(emb + (size_t)k * DD, 1);
}

// Scorer: block = 256 threads = 4 waves, 64 queries (lane = query).
// Wave r handles codes k = 16*i + 4*r + j, j=0..3 (4 fma chains per thread).
// Each dot is a strict sequential fp32 fma chain over d = 0..255 (BLAS order).
// dist = fl(fl(A+B) - 2*C); argmin with first-index tie-break.
__global__ __launch_bounds__(256) void score3_kernel(
    const float* __restrict__ z_e, const float* __restrict__ emb,
    const float* __restrict__ Bf, float* __restrict__ out_idx,
    int* __restrict__ idx_i, double* __restrict__ loss_acc) {
    __shared__ float smem[20480];          // 80 KiB: zl[256][64] + es[4][4][256]
    float* zl = smem;                      // zl[d*64 + q]
    float* es = smem + 16384;              // es[wave][j][d]

    const int t    = threadIdx.x;
    const int lane = t & 63;
    const int r    = t >> 6;
    const int n0   = blockIdx.x * 64;
    const int b    = n0 >> 10;
    const int t0   = n0 & 1023;

    // stage z tile (coalesced: lane = t-index)
    for (int d = r; d < DD; d += 4)
        zl[d * 64 + lane] = z_e[(size_t)(b * DD + d) * TT + t0 + lane];
    __syncthreads();

    // A_n: numpy pairwise fp32 sum of z^2 (stride-64 reads from LDS)
    const float A = np_sq_sum256(zl + lane, 64);

    float best = 3.0e38f;
    int   bidx = 0;
    float* et = es + r * 1024;             // this wave's private e tile
    const int row = lane >> 4;             // staging: 4 rows x 16 lanes x 4 float4
    const int c4  = lane & 15;

    for (int i = 0; i < KK / 16; ++i) {
        const int k0 = 16 * i + 4 * r;
        // stage e rows k0..k0+3 into wave-private LDS (no barrier needed)
        {
            const float4* src = reinterpret_cast<const float4*>(emb + (size_t)(k0 + row) * DD);
            float4* dst = reinterpret_cast<float4*>(et + row * DD);
            #pragma unroll
            for (int m = 0; m < 4; ++m) dst[c4 + 16 * m] = src[c4 + 16 * m];
        }
        float c0 = 0.0f, c1 = 0.0f, c2 = 0.0f, c3 = 0.0f;
        #pragma unroll 4
        for (int d = 0; d < DD; ++d) {
            const float zv = zl[d * 64 + lane];
            c0 = __fmaf_rn(zv, et[0 * DD + d], c0);
            c1 = __fmaf_rn(zv, et[1 * DD + d], c1);
            c2 = __fmaf_rn(zv, et[2 * DD + d], c2);
            c3 = __fmaf_rn(zv, et[3 * DD + d], c3);
        }
        float cs[4] = {c0, c1, c2, c3};
        #pragma unroll
        for (int j = 0; j < 4; ++j) {
            const float t1   = __fadd_rn(A, Bf[k0 + j]);
            const float m2   = __fadd_rn(cs[j], cs[j]);   // 2C exact
            const float dist = __fsub_rn(t1, m2);
            if (dist < best) { best = dist; bidx = k0 + j; }  // k ascending -> first min
        }
    }

    // merge across the 4 waves (reuse smem; zl is dead now)
    __syncthreads();
    float*  sb = smem;                     // [4][64]
    int*    si = reinterpret_cast<int*>(smem + 256);
    double* ls = reinterpret_cast<double*>(smem + 512);
    sb[r * 64 + lane] = best;
    si[r * 64 + lane] = bidx;
    __syncthreads();
    if (r == 0) {
        float bb = sb[lane];
        int   bi = si[lane];
        #pragma unroll
        for (int rr = 1; rr < 4; ++rr) {
            const float ob = sb[rr * 64 + lane];
            const int   oi = si[rr * 64 + lane];
            if (ob < bb || (ob == bb && oi < bi)) { bb = ob; bi = oi; }
        }
        const int n = n0 + lane;
        out_idx[n] = (float)bi;
        idx_i[n]   = bi;
        ls[lane]   = (double)bb;           // min dist = ||z - e||^2 (to fp32 rounding)
    }
    __syncthreads();
    if (t == 0) {
        double s = 0.0;
        for (int q = 0; q < 64; ++q) s += ls[q];
        atomicAdd(loss_acc, s);
    }
}

__global__ __launch_bounds__(256) void gather_kernel(const float* __restrict__ emb,
                                                     const int* __restrict__ idx_i,
                                                     float* __restrict__ zq) {
    const int blk = blockIdx.x;
    const int b  = blk >> 4;
    const int t0 = (blk & 15) * 64;
    const int q  = threadIdx.x & 63;
    const int dc = threadIdx.x >> 6;
    const int n  = b * TT + t0 + q;
    const int k  = idx_i[n];
    const float4* erow = reinterpret_cast<const float4*>(emb + (size_t)k * DD + dc * 64);
    #pragma unroll
    for (int jj = 0; jj < 16; ++jj) {
        const float4 v = erow[jj];
        const int d = dc * 64 + jj * 4;
        zq[(size_t)(b * DD + d + 0) * TT + t0 + q] = v.x;
        zq[(size_t)(b * DD + d + 1) * TT + t0 + q] = v.y;
        zq[(size_t)(b * DD + d + 2) * TT + t0 + q] = v.z;
        zq[(size_t)(b * DD + d + 3) * TT + t0 + q] = v.w;
    }
}

__global__ void fin_kernel(const double* __restrict__ loss_acc,
                           float* __restrict__ out_loss) {
    out_loss[0] = (float)(loss_acc[0] * (1.0 / ((double)BB * DD * TT)));
}

extern "C" void kernel_launch(void* const* d_in, const int* in_sizes, int n_in,
                              void* d_out, int out_size, void* d_ws, size_t ws_size,
                              hipStream_t stream) {
    const float* z_e = (const float*)d_in[0];
    const float* emb = (const float*)d_in[1];

    float* out      = (float*)d_out;
    float* zq       = out;
    float* out_loss = out + (size_t)BB * DD * TT;
    float* out_idx  = out_loss + 1;

    double* loss_acc = (double*)d_ws;
    float*  Bf       = (float*)((char*)d_ws + 64);
    int*    idx_i    = (int*)((char*)d_ws + 64 + (size_t)KK * 4);

    hipMemsetAsync(d_ws, 0, 64, stream);
    bsum_kernel<<<KK / 256, 256, 0, stream>>>(emb, Bf);
    score3_kernel<<<(BB * TT) / 64, 256, 0, stream>>>(z_e, emb, Bf, out_idx, idx_i, loss_acc);
    gather_kernel<<<(BB * TT) / 64, 256, 0, stream>>>(emb, idx_i, zq);
    fin_kernel<<<1, 1, 0, stream>>>(loss_acc, out_loss);
}